// Round 8
// baseline (205.822 us; speedup 1.0000x reference)
//
#include <hip/hip_runtime.h>

typedef __bf16 bf16x8 __attribute__((ext_vector_type(8)));
typedef __bf16 bf16x2 __attribute__((ext_vector_type(2)));
typedef float f32x4 __attribute__((ext_vector_type(4)));
typedef float f32x16 __attribute__((ext_vector_type(16)));
typedef unsigned short ushort;

__device__ __forceinline__ int4 cvt8(float4 a, float4 b) {
  bf16x8 v;
  v[0] = (__bf16)a.x; v[1] = (__bf16)a.y; v[2] = (__bf16)a.z; v[3] = (__bf16)a.w;
  v[4] = (__bf16)b.x; v[5] = (__bf16)b.y; v[6] = (__bf16)b.z; v[7] = (__bf16)b.w;
  return __builtin_bit_cast(int4, v);
}

__device__ __forceinline__ void gld16(const void* g, void* l) {
  __builtin_amdgcn_global_load_lds(
      (const __attribute__((address_space(1))) void*)g,
      (__attribute__((address_space(3))) void*)l, 16, 0, 0);
}

// pack 2 f32 -> 1 dword of 2 bf16 (compiler emits v_cvt_pk_bf16_f32)
__device__ __forceinline__ unsigned pkbf(float a, float b) {
  bf16x2 v;
  v[0] = (__bf16)a;
  v[1] = (__bf16)b;
  return __builtin_bit_cast(unsigned, v);
}

// exchange: after call a = [a_lo | b_lo], b = [a_hi | b_hi] (32-lane halves)
#if __has_builtin(__builtin_amdgcn_permlane32_swap)
typedef unsigned u32x2 __attribute__((ext_vector_type(2)));
__device__ __forceinline__ void plswap(unsigned& a, unsigned& b, int hi) {
  (void)hi;
  u32x2 r = __builtin_amdgcn_permlane32_swap(a, b, false, false);
  a = r[0]; b = r[1];
}
#else
__device__ __forceinline__ void plswap(unsigned& a, unsigned& b, int hi) {
  const unsigned pa = (unsigned)__shfl_xor((int)a, 32);
  const unsigned pb = (unsigned)__shfl_xor((int)b, 32);
  const unsigned x = hi ? pb : a;
  const unsigned y = hi ? b : pa;
  a = x; b = y;
}
#endif

__device__ __forceinline__ f32x16 mfma32(bf16x8 a, bf16x8 b, f32x16 c) {
  return __builtin_amdgcn_mfma_f32_32x32x16_bf16(a, b, c, 0, 0, 0);
}

// 4 weight matrices fp32 -> bf16 in one launch (grid.y picks the matrix)
__global__ __launch_bounds__(256) void cvt4_k(const float* __restrict__ i0,
                                              const float* __restrict__ i1,
                                              const float* __restrict__ i2,
                                              const float* __restrict__ i3,
                                              ushort* __restrict__ o, int n8) {
  const int z = blockIdx.y;
  const float* in = (z == 0) ? i0 : (z == 1) ? i1 : (z == 2) ? i2 : i3;
  ushort* out = o + (size_t)z * 1024 * 1024;
  int i = blockIdx.x * 256 + threadIdx.x;
  if (i >= n8) return;
  const float4* p = (const float4*)in + (size_t)i * 2;
  *(int4*)(out + (size_t)i * 8) = cvt8(p[0], p[1]);
}

// ---- shared GEMM body: C = (A @ W^T + bias) * oscale, M=8192, N=K=1024 ----
// AMODE 0: A fp32 (reg-staged+cvt); 1: A bf16 (global_load_lds).
// omode 0: bf16 [B,H,S,HD]; 1: bf16 [B,H,HD,S]; 2: fp32 [M,N].
template <int AMODE>
__device__ __forceinline__ void gemm_body(const void* __restrict__ A,
                                          const ushort* __restrict__ W,
                                          const float* __restrict__ bias,
                                          void* __restrict__ Out, float oscale,
                                          int omode, char* lA, char* lB) {
  constexpr int K = 1024;
  const int t = threadIdx.x;
  const int l = t & 63;
  const int w = t >> 6;
  const int wr = w >> 1, wc = w & 1;
  const int m0 = blockIdx.x * 128;
  const int n0 = blockIdx.y * 128;
  const int srow = l >> 3;
  const int scol = ((l & 7) ^ srow) << 3;
  f32x4 acc[4][4];
#pragma unroll
  for (int i = 0; i < 4; ++i)
#pragma unroll
    for (int j = 0; j < 4; ++j) acc[i][j] = (f32x4){0.f, 0.f, 0.f, 0.f};

  for (int k0 = 0; k0 < K; k0 += 64) {
    if constexpr (AMODE == 1) {
#pragma unroll
      for (int i = 0; i < 4; ++i) {
        const int chunk = w * 4 + i;
        gld16((const ushort*)A + (size_t)(m0 + chunk * 8 + srow) * K + k0 + scol,
              lA + chunk * 1024);
      }
    } else {
#pragma unroll
      for (int qq = 0; qq < 4; ++qq) {
        const int L = t * 8 + qq * 2048;
        const int r = L >> 6, c = L & 63;
        const int dst = r * 128 + ((c * 2) ^ ((r & 7) << 4));
        const float* s0 = (const float*)A + (size_t)(m0 + r) * K + k0 + c;
        *(int4*)(lA + dst) = cvt8(*(const float4*)s0, *(const float4*)(s0 + 4));
      }
    }
#pragma unroll
    for (int i = 0; i < 4; ++i) {
      const int chunk = w * 4 + i;
      gld16(W + (size_t)(n0 + chunk * 8 + srow) * K + k0 + scol, lB + chunk * 1024);
    }
    __syncthreads();
#pragma unroll
    for (int ks = 0; ks < 2; ++ks) {
      const int kb = ks * 64 + ((l >> 4) << 4);
      bf16x8 af[4], bfv[4];
#pragma unroll
      for (int i = 0; i < 4; ++i) {
        const int row = wr * 64 + i * 16 + (l & 15);
        af[i] = *(const bf16x8*)(lA + row * 128 + (kb ^ ((row & 7) << 4)));
      }
#pragma unroll
      for (int j = 0; j < 4; ++j) {
        const int row = wc * 64 + j * 16 + (l & 15);
        bfv[j] = *(const bf16x8*)(lB + row * 128 + (kb ^ ((row & 7) << 4)));
      }
#pragma unroll
      for (int i = 0; i < 4; ++i)
#pragma unroll
        for (int j = 0; j < 4; ++j)
          acc[i][j] = __builtin_amdgcn_mfma_f32_16x16x32_bf16(af[i], bfv[j],
                                                              acc[i][j], 0, 0, 0);
    }
    __syncthreads();
  }
#pragma unroll
  for (int i = 0; i < 4; ++i)
#pragma unroll
    for (int j = 0; j < 4; ++j)
#pragma unroll
      for (int rg = 0; rg < 4; ++rg) {
        const int gm = m0 + wr * 64 + i * 16 + ((l >> 4) << 2) + rg;
        const int gn = n0 + wc * 64 + j * 16 + (l & 15);
        const float v = (acc[i][j][rg] + bias[gn]) * oscale;
        if (omode == 0) {
          const int b = gm >> 11, s = gm & 2047, h = gn >> 6, hd = gn & 63;
          ((ushort*)Out)[((((size_t)(b * 16 + h)) * 2048 + s) << 6) + hd] =
              __builtin_bit_cast(ushort, (__bf16)v);
        } else if (omode == 1) {
          const int b = gm >> 11, s = gm & 2047, h = gn >> 6, hd = gn & 63;
          ((ushort*)Out)[((((size_t)(b * 16 + h)) << 6) + hd) * 2048 + s] =
              __builtin_bit_cast(ushort, (__bf16)v);
        } else {
          ((float*)Out)[(size_t)gm * 1024 + gn] = v;
        }
      }
}

// fused QKV projections: grid.z picks {query->qh, key->kh, value->vt}
__global__ __launch_bounds__(256) void gemmQKV_k(
    const float* __restrict__ Aq, const float* __restrict__ Ak,
    const float* __restrict__ Av, const ushort* __restrict__ Wb,
    const float* __restrict__ bq, const float* __restrict__ bk,
    const float* __restrict__ bv, ushort* __restrict__ qh,
    ushort* __restrict__ kh, ushort* __restrict__ vt, float qs) {
  __shared__ __align__(16) char lA[128 * 128];
  __shared__ __align__(16) char lB[128 * 128];
  const int z = blockIdx.z;
  const float* A = (z == 0) ? Aq : (z == 1) ? Ak : Av;
  const float* bias = (z == 0) ? bq : (z == 1) ? bk : bv;
  void* Out = (z == 0) ? (void*)qh : (z == 1) ? (void*)kh : (void*)vt;
  gemm_body<0>(A, Wb + (size_t)z * 1024 * 1024, bias, Out,
               (z == 0) ? qs : 1.0f, (z == 2) ? 1 : 0, lA, lB);
}

// O projection: bf16 A (gld16), fp32 out
__global__ __launch_bounds__(256) void gemmO_k(const ushort* __restrict__ A,
                                               const ushort* __restrict__ W,
                                               const float* __restrict__ bias,
                                               float* __restrict__ Out) {
  __shared__ __align__(16) char lA[128 * 128];
  __shared__ __align__(16) char lB[128 * 128];
  gemm_body<1>(A, W, bias, Out, 1.0f, 2, lA, lB);
}

// Flash attention, causal. qh (PRE-SCALED by 0.125*log2e): [B,H,S,HD] bf16.
// kh: [B,H,S,HD] bf16. vth: [B,H,HD,S] bf16. out: [B,S,D] bf16.
// 128 thr = 2 waves x 32 q-rows (QBLK=64). Swapped-operand MFMA 32x32x16,
// in-register softmax, P via v_cvt_pk+permlane32_swap. KVBLK=64 dbuf (T14).
// Uniform work: block (bh, y) does q-tile pair {31-y, y} = 33 KV-tiles.
__global__ __launch_bounds__(128) void attn_k(const ushort* __restrict__ qh,
                                              const ushort* __restrict__ kh,
                                              const ushort* __restrict__ vth,
                                              ushort* __restrict__ out) {
  const int bh = blockIdx.x;  // b*16 + h (fastest dim)
  const int t = threadIdx.x, l = t & 63, wv = t >> 6;  // wv in {0,1}
  const int lq = l & 31, hi = l >> 5;
  __shared__ __align__(16) char lk[2][64 * 128];
  __shared__ __align__(16) char lv[2][64 * 128];

  // staging geometry: 128 thr x 8 int4 = 16KB (K 8KB + V 8KB)
  const int r0 = t >> 1;            // 0..63 (row)
  const int cq = (t & 1) * 32;      // elem col base {0,32}
  const ushort* kbase = kh + (size_t)bh * 2048 * 64 + (size_t)r0 * 64 + cq;
  const ushort* vbase = vth + (size_t)bh * 64 * 2048 + (size_t)r0 * 2048 + cq;
  const int swz = (r0 & 7) << 4;
  const int d0 = r0 * 128 + ((cq * 2 + 0) ^ swz);
  const int d1 = r0 * 128 + ((cq * 2 + 16) ^ swz);
  const int d2 = r0 * 128 + ((cq * 2 + 32) ^ swz);
  const int d3 = r0 * 128 + ((cq * 2 + 48) ^ swz);
  const int b = bh >> 4, h = bh & 15;

  int4 ka0, ka1, ka2, ka3, va0, va1, va2, va3;  // named -> stay in VGPRs
#define LOAD_TILE(kv0)                                      \
  do {                                                      \
    const ushort* kp = kbase + (size_t)(kv0) * 64;          \
    const ushort* vp = vbase + (kv0);                       \
    ka0 = *(const int4*)(kp);                               \
    ka1 = *(const int4*)(kp + 8);                           \
    ka2 = *(const int4*)(kp + 16);                          \
    ka3 = *(const int4*)(kp + 24);                          \
    va0 = *(const int4*)(vp);                               \
    va1 = *(const int4*)(vp + 8);                           \
    va2 = *(const int4*)(vp + 16);                          \
    va3 = *(const int4*)(vp + 24);                          \
  } while (0)
#define WRITE_TILE(buf)                                     \
  do {                                                      \
    *(int4*)(lk[buf] + d0) = ka0;                           \
    *(int4*)(lk[buf] + d1) = ka1;                           \
    *(int4*)(lk[buf] + d2) = ka2;                           \
    *(int4*)(lk[buf] + d3) = ka3;                           \
    *(int4*)(lv[buf] + d0) = va0;                           \
    *(int4*)(lv[buf] + d1) = va1;                           \
    *(int4*)(lv[buf] + d2) = va2;                           \
    *(int4*)(lv[buf] + d3) = va3;                           \
  } while (0)

#pragma unroll 1
  for (int pass = 0; pass < 2; ++pass) {
    const int qt = pass ? blockIdx.y : (31 - blockIdx.y);
    const int q0 = qt * 64;
    const int qwave = q0 + wv * 32;      // wave's q-row base
    const int qrow = qwave + lq;         // this lane's q (output col of S^T)

    // Q as B-operand: col = l&31 = q, k(d) = kd*16 + hi*8 + 0..7
    bf16x8 qf0, qf1, qf2, qf3;
    {
      const ushort* qp = qh + ((size_t)bh * 2048 + qrow) * 64 + hi * 8;
      qf0 = *(const bf16x8*)(qp);
      qf1 = *(const bf16x8*)(qp + 16);
      qf2 = *(const bf16x8*)(qp + 32);
      qf3 = *(const bf16x8*)(qp + 48);
    }
    LOAD_TILE(0);
    __syncthreads();  // prior pass done reading LDS
    WRITE_TILE(0);

    float m_r = -1e30f, l_r = 0.f;
    f32x16 acco[2];
#pragma unroll
    for (int dt = 0; dt < 2; ++dt)
#pragma unroll
      for (int r = 0; r < 16; ++r) acco[dt][r] = 0.f;

    const int nt = qt + 1;  // 64-wide KV tiles
    int cur = 0;
#pragma unroll 1
    for (int ti = 0; ti < nt; ++ti) {
      __syncthreads();  // buf[cur] visible; buf[cur^1] free
      if (ti + 1 < nt) LOAD_TILE((ti + 1) << 6);

#pragma unroll
      for (int s = 0; s < 2; ++s) {
        const int kvs = (ti << 6) + s * 32;
        if (kvs > qwave + 31) continue;  // wave-uniform: above diagonal

        // S^T[kv_local][q] = K_tile . Q^T  (4 k-steps over d=64)
        f32x16 p;
#pragma unroll
        for (int r = 0; r < 16; ++r) p[r] = 0.f;
#pragma unroll
        for (int kd = 0; kd < 4; ++kd) {
          const int row = s * 32 + lq;
          const bf16x8 kf = *(const bf16x8*)(
              lk[cur] + row * 128 + ((kd * 32 + hi * 16) ^ ((row & 7) << 4)));
          const bf16x8 qf = (kd == 0) ? qf0 : (kd == 1) ? qf1 : (kd == 2) ? qf2 : qf3;
          p = mfma32(kf, qf, p);
        }
        // causal mask: kv = kvs + (r&3) + 8*(r>>2) + 4*hi ; mask if kv > qrow
        if (kvs + 31 > qwave) {
#pragma unroll
          for (int r = 0; r < 16; ++r) {
            const int kv = kvs + (r & 3) + 8 * (r >> 2) + 4 * hi;
            if (kv > qrow) p[r] = -1e30f;
          }
        }
        // row max: max3-fused tree (8 ops) + cross-hi
        const float a0 = fmaxf(fmaxf(p[0], p[1]), p[2]);
        const float a1 = fmaxf(fmaxf(p[3], p[4]), p[5]);
        const float a2 = fmaxf(fmaxf(p[6], p[7]), p[8]);
        const float a3 = fmaxf(fmaxf(p[9], p[10]), p[11]);
        const float a4 = fmaxf(fmaxf(p[12], p[13]), p[14]);
        const float b0 = fmaxf(fmaxf(a0, a1), a2);
        const float b1 = fmaxf(fmaxf(a3, a4), p[15]);
        float tm = fmaxf(b0, b1);
        tm = fmaxf(tm, __shfl_xor(tm, 32));
        // defer-max (T13): only rescale when max grew by > 8 (exp2 domain)
        if (!__all(tm <= m_r + 8.f)) {
          const float mn = fmaxf(m_r, tm);
          const float e = __builtin_amdgcn_exp2f(m_r - mn);
          m_r = mn;
          l_r *= e;
#pragma unroll
          for (int dt = 0; dt < 2; ++dt)
#pragma unroll
            for (int r = 0; r < 16; ++r) acco[dt][r] *= e;
        }
        // p = exp2(S - m); VALU row-sum tree
#pragma unroll
        for (int r = 0; r < 16; ++r) p[r] = __builtin_amdgcn_exp2f(p[r] - m_r);
        float sr[8];
#pragma unroll
        for (int r = 0; r < 8; ++r) sr[r] = p[r] + p[r + 8];
#pragma unroll
        for (int r = 0; r < 4; ++r) sr[r] = sr[r] + sr[r + 4];
        float rs = (sr[0] + sr[1]) + (sr[2] + sr[3]);
        rs += __shfl_xor(rs, 32);
        l_r += rs;
        // pack P pairs: W[j][i] holds kv = 8j + 4hi + 2i + {0,1}
        unsigned W0a = pkbf(p[0], p[1]),   W0b = pkbf(p[2], p[3]);
        unsigned W1a = pkbf(p[4], p[5]),   W1b = pkbf(p[6], p[7]);
        unsigned W2a = pkbf(p[8], p[9]),   W2b = pkbf(p[10], p[11]);
        unsigned W3a = pkbf(p[12], p[13]), W3b = pkbf(p[14], p[15]);
        // PV: O^T += V^T . P  (2 k-steps of 16 kv)
#pragma unroll
        for (int ks = 0; ks < 2; ++ks) {
          unsigned a0u = ks ? W2a : W0a;
          unsigned a1u = ks ? W2b : W0b;
          unsigned b0u = ks ? W3a : W1a;
          unsigned b1u = ks ? W3b : W1b;
          plswap(a0u, b0u, hi);
          plswap(a1u, b1u, hi);
          const uint4 pw = {a0u, a1u, b0u, b1u};
          const bf16x8 pf = __builtin_bit_cast(bf16x8, pw);
#pragma unroll
          for (int dt = 0; dt < 2; ++dt) {
            const int row = dt * 32 + lq;
            const bf16x8 vf = *(const bf16x8*)(
                lv[cur] + row * 128 +
                ((s * 64 + ks * 32 + hi * 16) ^ ((row & 7) << 4)));
            acco[dt] = mfma32(vf, pf, acco[dt]);
          }
        }
      }
      if (ti + 1 < nt) WRITE_TILE(cur ^ 1);
      cur ^= 1;
    }
    // epilogue: O^T lane = (q=qrow, d = (r&3)+8*(r>>2)+4*hi+32*dt)
    const float inv = __builtin_amdgcn_rcpf(l_r);
    ushort* orow = out + ((size_t)(b * 2048 + qrow)) * 1024 + h * 64;
#pragma unroll
    for (int dt = 0; dt < 2; ++dt)
#pragma unroll
      for (int g = 0; g < 4; ++g) {
        ushort4 st;
        st.x = __builtin_bit_cast(ushort, (__bf16)(acco[dt][4 * g + 0] * inv));
        st.y = __builtin_bit_cast(ushort, (__bf16)(acco[dt][4 * g + 1] * inv));
        st.z = __builtin_bit_cast(ushort, (__bf16)(acco[dt][4 * g + 2] * inv));
        st.w = __builtin_bit_cast(ushort, (__bf16)(acco[dt][4 * g + 3] * inv));
        *(ushort4*)(orow + dt * 32 + g * 8 + hi * 4) = st;
      }
  }
#undef LOAD_TILE
#undef WRITE_TILE
}

// fallback GEMM (fp32 W, reg-staged) for small-ws path
template <int OMODE>
__global__ __launch_bounds__(256) void gemmF_k(const void* __restrict__ A,
                                               const float* __restrict__ W,
                                               const float* __restrict__ bias,
                                               void* __restrict__ Out,
                                               float oscale, int amode) {
  constexpr int K = 1024;
  __shared__ __align__(16) char lA[128 * 128];
  __shared__ __align__(16) char lB[128 * 128];
  const int t = threadIdx.x;
  const int l = t & 63;
  const int w = t >> 6;
  const int wr = w >> 1, wc = w & 1;
  const int m0 = blockIdx.x * 128;
  const int n0 = blockIdx.y * 128;
  f32x4 acc[4][4];
#pragma unroll
  for (int i = 0; i < 4; ++i)
#pragma unroll
    for (int j = 0; j < 4; ++j) acc[i][j] = (f32x4){0.f, 0.f, 0.f, 0.f};
  for (int k0 = 0; k0 < K; k0 += 64) {
#pragma unroll
    for (int qq = 0; qq < 4; ++qq) {
      const int L = t * 8 + qq * 2048;
      const int r = L >> 6, c = L & 63;
      const int dst = r * 128 + ((c * 2) ^ ((r & 7) << 4));
      if (amode == 0) {
        const float* s0 = (const float*)A + (size_t)(m0 + r) * K + k0 + c;
        *(int4*)(lA + dst) = cvt8(*(const float4*)s0, *(const float4*)(s0 + 4));
      } else {
        *(int4*)(lA + dst) =
            *(const int4*)((const ushort*)A + (size_t)(m0 + r) * K + k0 + c);
      }
      const float* s1 = W + (size_t)(n0 + r) * K + k0 + c;
      *(int4*)(lB + dst) = cvt8(*(const float4*)s1, *(const float4*)(s1 + 4));
    }
    __syncthreads();
#pragma unroll
    for (int ks = 0; ks < 2; ++ks) {
      const int kb = ks * 64 + ((l >> 4) << 4);
      bf16x8 af[4], bfv[4];
#pragma unroll
      for (int i = 0; i < 4; ++i) {
        const int row = wr * 64 + i * 16 + (l & 15);
        af[i] = *(const bf16x8*)(lA + row * 128 + (kb ^ ((row & 7) << 4)));
      }
#pragma unroll
      for (int j = 0; j < 4; ++j) {
        const int row = wc * 64 + j * 16 + (l & 15);
        bfv[j] = *(const bf16x8*)(lB + row * 128 + (kb ^ ((row & 7) << 4)));
      }
#pragma unroll
      for (int i = 0; i < 4; ++i)
#pragma unroll
        for (int j = 0; j < 4; ++j)
          acc[i][j] = __builtin_amdgcn_mfma_f32_16x16x32_bf16(af[i], bfv[j],
                                                              acc[i][j], 0, 0, 0);
    }
    __syncthreads();
  }
#pragma unroll
  for (int i = 0; i < 4; ++i)
#pragma unroll
    for (int j = 0; j < 4; ++j)
#pragma unroll
      for (int rg = 0; rg < 4; ++rg) {
        const int gm = m0 + wr * 64 + i * 16 + ((l >> 4) << 2) + rg;
        const int gn = n0 + wc * 64 + j * 16 + (l & 15);
        const float v = (acc[i][j][rg] + bias[gn]) * oscale;
        if constexpr (OMODE == 0) {
          const int b = gm >> 11, s = gm & 2047, h = gn >> 6, hd = gn & 63;
          ((ushort*)Out)[((((size_t)(b * 16 + h)) * 2048 + s) << 6) + hd] =
              __builtin_bit_cast(ushort, (__bf16)v);
        } else if constexpr (OMODE == 1) {
          const int b = gm >> 11, s = gm & 2047, h = gn >> 6, hd = gn & 63;
          ((ushort*)Out)[((((size_t)(b * 16 + h)) << 6) + hd) * 2048 + s] =
              __builtin_bit_cast(ushort, (__bf16)v);
        } else {
          ((float*)Out)[(size_t)gm * 1024 + gn] = v;
        }
      }
}

extern "C" void kernel_launch(void* const* d_in, const int* in_sizes, int n_in,
                              void* d_out, int out_size, void* d_ws, size_t ws_size,
                              hipStream_t stream) {
  (void)in_sizes; (void)n_in; (void)out_size;
  const float* query = (const float*)d_in[0];
  const float* key = (const float*)d_in[1];
  const float* value = (const float*)d_in[2];
  const float* Wq = (const float*)d_in[4];
  const float* bq = (const float*)d_in[5];
  const float* Wk = (const float*)d_in[6];
  const float* bk = (const float*)d_in[7];
  const float* Wv = (const float*)d_in[8];
  const float* bv = (const float*)d_in[9];
  const float* Wo = (const float*)d_in[10];
  const float* bo = (const float*)d_in[11];

  char* ws = (char*)d_ws;
  const size_t SZA = (size_t)8192 * 1024 * 2;
  const size_t SZW = (size_t)1024 * 1024 * 2;
  ushort* qh = (ushort*)(ws + 0 * SZA);
  ushort* kh = (ushort*)(ws + 1 * SZA);
  ushort* vt = (ushort*)(ws + 2 * SZA);
  ushort* ao = (ushort*)(ws + 3 * SZA);
  dim3 gg(64, 8);
  const float QS = 0.125f * 1.44269504088896f;  // 1/sqrt(64) * log2(e)

  if (ws_size >= 4 * SZA + 4 * SZW) {
    ushort* wq = (ushort*)(ws + 4 * SZA);
    ushort* wo = (ushort*)(ws + 4 * SZA + 3 * SZW);
    const int n8w = 1024 * 1024 / 8;
    hipLaunchKernelGGL(cvt4_k, dim3(n8w / 256, 4), dim3(256), 0, stream,
                       Wq, Wk, Wv, Wo, wq, n8w);
    hipLaunchKernelGGL(gemmQKV_k, dim3(64, 8, 3), dim3(256), 0, stream,
                       query, key, value, wq, bq, bk, bv, qh, kh, vt, QS);
    hipLaunchKernelGGL(attn_k, dim3(64, 16), dim3(128), 0, stream, qh, kh, vt, ao);
    hipLaunchKernelGGL(gemmO_k, gg, dim3(256), 0, stream, ao, wo, bo, (float*)d_out);
  } else {
    hipLaunchKernelGGL((gemmF_k<0>), gg, dim3(256), 0, stream, (const void*)query, Wq, bq, (void*)qh, QS, 0);
    hipLaunchKernelGGL((gemmF_k<0>), gg, dim3(256), 0, stream, (const void*)key, Wk, bk, (void*)kh, 1.0f, 0);
    hipLaunchKernelGGL((gemmF_k<1>), gg, dim3(256), 0, stream, (const void*)value, Wv, bv, (void*)vt, 1.0f, 0);
    hipLaunchKernelGGL(attn_k, dim3(64, 16), dim3(128), 0, stream, qh, kh, vt, ao);
    hipLaunchKernelGGL((gemmF_k<2>), gg, dim3(256), 0, stream, (const void*)ao, Wo, bo, d_out, 1.0f, 1);
  }
}

// Round 9
// 202.159 us; speedup vs baseline: 1.0181x; 1.0181x over previous
//
#include <hip/hip_runtime.h>

typedef __bf16 bf16x8 __attribute__((ext_vector_type(8)));
typedef __bf16 bf16x2 __attribute__((ext_vector_type(2)));
typedef float f32x4 __attribute__((ext_vector_type(4)));
typedef float f32x16 __attribute__((ext_vector_type(16)));
typedef unsigned short ushort;

__device__ __forceinline__ int4 cvt8(float4 a, float4 b) {
  bf16x8 v;
  v[0] = (__bf16)a.x; v[1] = (__bf16)a.y; v[2] = (__bf16)a.z; v[3] = (__bf16)a.w;
  v[4] = (__bf16)b.x; v[5] = (__bf16)b.y; v[6] = (__bf16)b.z; v[7] = (__bf16)b.w;
  return __builtin_bit_cast(int4, v);
}

__device__ __forceinline__ void gld16(const void* g, void* l) {
  __builtin_amdgcn_global_load_lds(
      (const __attribute__((address_space(1))) void*)g,
      (__attribute__((address_space(3))) void*)l, 16, 0, 0);
}

// pack 2 f32 -> 1 dword of 2 bf16 (compiler emits v_cvt_pk_bf16_f32)
__device__ __forceinline__ unsigned pkbf(float a, float b) {
  bf16x2 v;
  v[0] = (__bf16)a;
  v[1] = (__bf16)b;
  return __builtin_bit_cast(unsigned, v);
}

// exchange: after call a = [a_lo | b_lo], b = [a_hi | b_hi] (32-lane halves)
#if __has_builtin(__builtin_amdgcn_permlane32_swap)
typedef unsigned u32x2 __attribute__((ext_vector_type(2)));
__device__ __forceinline__ void plswap(unsigned& a, unsigned& b, int hi) {
  (void)hi;
  u32x2 r = __builtin_amdgcn_permlane32_swap(a, b, false, false);
  a = r[0]; b = r[1];
}
#else
__device__ __forceinline__ void plswap(unsigned& a, unsigned& b, int hi) {
  const unsigned pa = (unsigned)__shfl_xor((int)a, 32);
  const unsigned pb = (unsigned)__shfl_xor((int)b, 32);
  const unsigned x = hi ? pb : a;
  const unsigned y = hi ? b : pa;
  a = x; b = y;
}
#endif

__device__ __forceinline__ f32x16 mfma32(bf16x8 a, bf16x8 b, f32x16 c) {
  return __builtin_amdgcn_mfma_f32_32x32x16_bf16(a, b, c, 0, 0, 0);
}

// 4 weight matrices fp32 -> bf16 in one launch (grid.y picks the matrix)
__global__ __launch_bounds__(256) void cvt4_k(const float* __restrict__ i0,
                                              const float* __restrict__ i1,
                                              const float* __restrict__ i2,
                                              const float* __restrict__ i3,
                                              ushort* __restrict__ o, int n8) {
  const int z = blockIdx.y;
  const float* in = (z == 0) ? i0 : (z == 1) ? i1 : (z == 2) ? i2 : i3;
  ushort* out = o + (size_t)z * 1024 * 1024;
  int i = blockIdx.x * 256 + threadIdx.x;
  if (i >= n8) return;
  const float4* p = (const float4*)in + (size_t)i * 2;
  *(int4*)(out + (size_t)i * 8) = cvt8(p[0], p[1]);
}

// C = (A @ W^T + bias) * oscale. M=8192, N=K=1024.
// AMODE 0: A fp32 (reg-staged+cvt); 1: A bf16 (global_load_lds).
// WMODE 0: W fp32 (reg-staged+cvt); 1: W bf16 (global_load_lds).
// OMODE 0: bf16 [B,H,S,HD]; 1: bf16 [B,H,HD,S]; 2: fp32 [M,N].
template <int AMODE, int WMODE, int OMODE>
__global__ __launch_bounds__(256) void gemm_k(const void* __restrict__ A,
                                              const void* __restrict__ W,
                                              const float* __restrict__ bias,
                                              void* __restrict__ Out,
                                              float oscale) {
  constexpr int K = 1024;
  __shared__ __align__(16) char lA[128 * 128];
  __shared__ __align__(16) char lB[128 * 128];
  const int t = threadIdx.x;
  const int l = t & 63;
  const int w = t >> 6;
  const int wr = w >> 1, wc = w & 1;
  const int m0 = blockIdx.x * 128;
  const int n0 = blockIdx.y * 128;
  const int srow = l >> 3;
  const int scol = ((l & 7) ^ srow) << 3;
  f32x4 acc[4][4];
#pragma unroll
  for (int i = 0; i < 4; ++i)
#pragma unroll
    for (int j = 0; j < 4; ++j) acc[i][j] = (f32x4){0.f, 0.f, 0.f, 0.f};

  for (int k0 = 0; k0 < K; k0 += 64) {
    if constexpr (AMODE == 1) {
#pragma unroll
      for (int i = 0; i < 4; ++i) {
        const int chunk = w * 4 + i;
        gld16((const ushort*)A + (size_t)(m0 + chunk * 8 + srow) * K + k0 + scol,
              lA + chunk * 1024);
      }
    } else {
#pragma unroll
      for (int qq = 0; qq < 4; ++qq) {
        const int L = t * 8 + qq * 2048;
        const int r = L >> 6, c = L & 63;
        const int dst = r * 128 + ((c * 2) ^ ((r & 7) << 4));
        const float* s0 = (const float*)A + (size_t)(m0 + r) * K + k0 + c;
        *(int4*)(lA + dst) = cvt8(*(const float4*)s0, *(const float4*)(s0 + 4));
      }
    }
    if constexpr (WMODE == 1) {
#pragma unroll
      for (int i = 0; i < 4; ++i) {
        const int chunk = w * 4 + i;
        gld16((const ushort*)W + (size_t)(n0 + chunk * 8 + srow) * K + k0 + scol,
              lB + chunk * 1024);
      }
    } else {
#pragma unroll
      for (int qq = 0; qq < 4; ++qq) {
        const int L = t * 8 + qq * 2048;
        const int r = L >> 6, c = L & 63;
        const int dst = r * 128 + ((c * 2) ^ ((r & 7) << 4));
        const float* s1 = (const float*)W + (size_t)(n0 + r) * K + k0 + c;
        *(int4*)(lB + dst) = cvt8(*(const float4*)s1, *(const float4*)(s1 + 4));
      }
    }
    __syncthreads();
#pragma unroll
    for (int ks = 0; ks < 2; ++ks) {
      const int kb = ks * 64 + ((l >> 4) << 4);
      bf16x8 af[4], bfv[4];
#pragma unroll
      for (int i = 0; i < 4; ++i) {
        const int row = wr * 64 + i * 16 + (l & 15);
        af[i] = *(const bf16x8*)(lA + row * 128 + (kb ^ ((row & 7) << 4)));
      }
#pragma unroll
      for (int j = 0; j < 4; ++j) {
        const int row = wc * 64 + j * 16 + (l & 15);
        bfv[j] = *(const bf16x8*)(lB + row * 128 + (kb ^ ((row & 7) << 4)));
      }
#pragma unroll
      for (int i = 0; i < 4; ++i)
#pragma unroll
        for (int j = 0; j < 4; ++j)
          acc[i][j] = __builtin_amdgcn_mfma_f32_16x16x32_bf16(af[i], bfv[j],
                                                              acc[i][j], 0, 0, 0);
    }
    __syncthreads();
  }
#pragma unroll
  for (int i = 0; i < 4; ++i)
#pragma unroll
    for (int j = 0; j < 4; ++j)
#pragma unroll
      for (int rg = 0; rg < 4; ++rg) {
        const int gm = m0 + wr * 64 + i * 16 + ((l >> 4) << 2) + rg;
        const int gn = n0 + wc * 64 + j * 16 + (l & 15);
        const float v = (acc[i][j][rg] + bias[gn]) * oscale;
        if constexpr (OMODE == 0) {
          const int b = gm >> 11, s = gm & 2047, h = gn >> 6, hd = gn & 63;
          ((ushort*)Out)[((((size_t)(b * 16 + h)) * 2048 + s) << 6) + hd] =
              __builtin_bit_cast(ushort, (__bf16)v);
        } else if constexpr (OMODE == 1) {
          const int b = gm >> 11, s = gm & 2047, h = gn >> 6, hd = gn & 63;
          ((ushort*)Out)[((((size_t)(b * 16 + h)) << 6) + hd) * 2048 + s] =
              __builtin_bit_cast(ushort, (__bf16)v);
        } else {
          ((float*)Out)[(size_t)gm * 1024 + gn] = v;
        }
      }
}

// Flash attention, causal. qh (PRE-SCALED by 0.125*log2e): [B,H,S,HD] bf16.
// kh: [B,H,S,HD] bf16. vth: [B,H,HD,S] bf16. out: [B,S,D] bf16.
// 128 thr = 2 waves x 32 q-rows (QBLK=64). Swapped-operand MFMA 32x32x16,
// in-register softmax, P via v_cvt_pk+permlane32_swap. KVBLK=64 dbuf (T14).
// Uniform work: block (bh, y) does q-tile pair {31-y, y} = 33 KV-tiles.
__global__ __launch_bounds__(128) void attn_k(const ushort* __restrict__ qh,
                                              const ushort* __restrict__ kh,
                                              const ushort* __restrict__ vth,
                                              ushort* __restrict__ out) {
  const int bh = blockIdx.x;  // b*16 + h (fastest dim)
  const int t = threadIdx.x, l = t & 63, wv = t >> 6;  // wv in {0,1}
  const int lq = l & 31, hi = l >> 5;
  __shared__ __align__(16) char lk[2][64 * 128];
  __shared__ __align__(16) char lv[2][64 * 128];

  // staging geometry: 128 thr x 8 int4 = 16KB (K 8KB + V 8KB)
  const int r0 = t >> 1;            // 0..63 (row)
  const int cq = (t & 1) * 32;      // elem col base {0,32}
  const ushort* kbase = kh + (size_t)bh * 2048 * 64 + (size_t)r0 * 64 + cq;
  const ushort* vbase = vth + (size_t)bh * 64 * 2048 + (size_t)r0 * 2048 + cq;
  const int swz = (r0 & 7) << 4;
  const int d0 = r0 * 128 + ((cq * 2 + 0) ^ swz);
  const int d1 = r0 * 128 + ((cq * 2 + 16) ^ swz);
  const int d2 = r0 * 128 + ((cq * 2 + 32) ^ swz);
  const int d3 = r0 * 128 + ((cq * 2 + 48) ^ swz);
  const int b = bh >> 4, h = bh & 15;

  int4 ka0, ka1, ka2, ka3, va0, va1, va2, va3;  // named -> stay in VGPRs
#define LOAD_TILE(kv0)                                      \
  do {                                                      \
    const ushort* kp = kbase + (size_t)(kv0) * 64;          \
    const ushort* vp = vbase + (kv0);                       \
    ka0 = *(const int4*)(kp);                               \
    ka1 = *(const int4*)(kp + 8);                           \
    ka2 = *(const int4*)(kp + 16);                          \
    ka3 = *(const int4*)(kp + 24);                          \
    va0 = *(const int4*)(vp);                               \
    va1 = *(const int4*)(vp + 8);                           \
    va2 = *(const int4*)(vp + 16);                          \
    va3 = *(const int4*)(vp + 24);                          \
  } while (0)
#define WRITE_TILE(buf)                                     \
  do {                                                      \
    *(int4*)(lk[buf] + d0) = ka0;                           \
    *(int4*)(lk[buf] + d1) = ka1;                           \
    *(int4*)(lk[buf] + d2) = ka2;                           \
    *(int4*)(lk[buf] + d3) = ka3;                           \
    *(int4*)(lv[buf] + d0) = va0;                           \
    *(int4*)(lv[buf] + d1) = va1;                           \
    *(int4*)(lv[buf] + d2) = va2;                           \
    *(int4*)(lv[buf] + d3) = va3;                           \
  } while (0)

#pragma unroll 1
  for (int pass = 0; pass < 2; ++pass) {
    const int qt = pass ? blockIdx.y : (31 - blockIdx.y);
    const int q0 = qt * 64;
    const int qwave = q0 + wv * 32;      // wave's q-row base
    const int qrow = qwave + lq;         // this lane's q (output col of S^T)

    // Q as B-operand: col = l&31 = q, k(d) = kd*16 + hi*8 + 0..7
    bf16x8 qf0, qf1, qf2, qf3;
    {
      const ushort* qp = qh + ((size_t)bh * 2048 + qrow) * 64 + hi * 8;
      qf0 = *(const bf16x8*)(qp);
      qf1 = *(const bf16x8*)(qp + 16);
      qf2 = *(const bf16x8*)(qp + 32);
      qf3 = *(const bf16x8*)(qp + 48);
    }
    LOAD_TILE(0);
    __syncthreads();  // prior pass done reading LDS
    WRITE_TILE(0);

    float m_r = -1e30f, l_r = 0.f;
    f32x16 acco[2];
#pragma unroll
    for (int dt = 0; dt < 2; ++dt)
#pragma unroll
      for (int r = 0; r < 16; ++r) acco[dt][r] = 0.f;

    const int nt = qt + 1;  // 64-wide KV tiles
    int cur = 0;
#pragma unroll 1
    for (int ti = 0; ti < nt; ++ti) {
      __syncthreads();  // buf[cur] visible; buf[cur^1] free
      if (ti + 1 < nt) LOAD_TILE((ti + 1) << 6);

#pragma unroll
      for (int s = 0; s < 2; ++s) {
        const int kvs = (ti << 6) + s * 32;
        if (kvs > qwave + 31) continue;  // wave-uniform: above diagonal

        // S^T[kv_local][q] = K_tile . Q^T  (4 k-steps over d=64)
        f32x16 p;
#pragma unroll
        for (int r = 0; r < 16; ++r) p[r] = 0.f;
#pragma unroll
        for (int kd = 0; kd < 4; ++kd) {
          const int row = s * 32 + lq;
          const bf16x8 kf = *(const bf16x8*)(
              lk[cur] + row * 128 + ((kd * 32 + hi * 16) ^ ((row & 7) << 4)));
          const bf16x8 qf = (kd == 0) ? qf0 : (kd == 1) ? qf1 : (kd == 2) ? qf2 : qf3;
          p = mfma32(kf, qf, p);
        }
        // causal mask: kv = kvs + (r&3) + 8*(r>>2) + 4*hi ; mask if kv > qrow
        if (kvs + 31 > qwave) {
#pragma unroll
          for (int r = 0; r < 16; ++r) {
            const int kv = kvs + (r & 3) + 8 * (r >> 2) + 4 * hi;
            if (kv > qrow) p[r] = -1e30f;
          }
        }
        // row max: max3-fused tree (8 ops) + cross-hi
        const float a0 = fmaxf(fmaxf(p[0], p[1]), p[2]);
        const float a1 = fmaxf(fmaxf(p[3], p[4]), p[5]);
        const float a2 = fmaxf(fmaxf(p[6], p[7]), p[8]);
        const float a3 = fmaxf(fmaxf(p[9], p[10]), p[11]);
        const float a4 = fmaxf(fmaxf(p[12], p[13]), p[14]);
        const float b0 = fmaxf(fmaxf(a0, a1), a2);
        const float b1 = fmaxf(fmaxf(a3, a4), p[15]);
        float tm = fmaxf(b0, b1);
        tm = fmaxf(tm, __shfl_xor(tm, 32));
        // defer-max (T13): only rescale when max grew by > 8 (exp2 domain)
        if (!__all(tm <= m_r + 8.f)) {
          const float mn = fmaxf(m_r, tm);
          const float e = __builtin_amdgcn_exp2f(m_r - mn);
          m_r = mn;
          l_r *= e;
#pragma unroll
          for (int dt = 0; dt < 2; ++dt)
#pragma unroll
            for (int r = 0; r < 16; ++r) acco[dt][r] *= e;
        }
        // p = exp2(S - m); VALU row-sum tree
#pragma unroll
        for (int r = 0; r < 16; ++r) p[r] = __builtin_amdgcn_exp2f(p[r] - m_r);
        float sr[8];
#pragma unroll
        for (int r = 0; r < 8; ++r) sr[r] = p[r] + p[r + 8];
#pragma unroll
        for (int r = 0; r < 4; ++r) sr[r] = sr[r] + sr[r + 4];
        float rs = (sr[0] + sr[1]) + (sr[2] + sr[3]);
        rs += __shfl_xor(rs, 32);
        l_r += rs;
        // pack P pairs: W[j][i] holds kv = 8j + 4hi + 2i + {0,1}
        unsigned W0a = pkbf(p[0], p[1]),   W0b = pkbf(p[2], p[3]);
        unsigned W1a = pkbf(p[4], p[5]),   W1b = pkbf(p[6], p[7]);
        unsigned W2a = pkbf(p[8], p[9]),   W2b = pkbf(p[10], p[11]);
        unsigned W3a = pkbf(p[12], p[13]), W3b = pkbf(p[14], p[15]);
        // PV: O^T += V^T . P  (2 k-steps of 16 kv)
#pragma unroll
        for (int ks = 0; ks < 2; ++ks) {
          unsigned a0u = ks ? W2a : W0a;
          unsigned a1u = ks ? W2b : W0b;
          unsigned b0u = ks ? W3a : W1a;
          unsigned b1u = ks ? W3b : W1b;
          plswap(a0u, b0u, hi);
          plswap(a1u, b1u, hi);
          const uint4 pw = {a0u, a1u, b0u, b1u};
          const bf16x8 pf = __builtin_bit_cast(bf16x8, pw);
#pragma unroll
          for (int dt = 0; dt < 2; ++dt) {
            const int row = dt * 32 + lq;
            const bf16x8 vf = *(const bf16x8*)(
                lv[cur] + row * 128 +
                ((s * 64 + ks * 32 + hi * 16) ^ ((row & 7) << 4)));
            acco[dt] = mfma32(vf, pf, acco[dt]);
          }
        }
      }
      if (ti + 1 < nt) WRITE_TILE(cur ^ 1);
      cur ^= 1;
    }
    // epilogue: O^T lane = (q=qrow, d = (r&3)+8*(r>>2)+4*hi+32*dt)
    const float inv = __builtin_amdgcn_rcpf(l_r);
    ushort* orow = out + ((size_t)(b * 2048 + qrow)) * 1024 + h * 64;
#pragma unroll
    for (int dt = 0; dt < 2; ++dt)
#pragma unroll
      for (int g = 0; g < 4; ++g) {
        ushort4 st;
        st.x = __builtin_bit_cast(ushort, (__bf16)(acco[dt][4 * g + 0] * inv));
        st.y = __builtin_bit_cast(ushort, (__bf16)(acco[dt][4 * g + 1] * inv));
        st.z = __builtin_bit_cast(ushort, (__bf16)(acco[dt][4 * g + 2] * inv));
        st.w = __builtin_bit_cast(ushort, (__bf16)(acco[dt][4 * g + 3] * inv));
        *(ushort4*)(orow + dt * 32 + g * 8 + hi * 4) = st;
      }
  }
#undef LOAD_TILE
#undef WRITE_TILE
}

extern "C" void kernel_launch(void* const* d_in, const int* in_sizes, int n_in,
                              void* d_out, int out_size, void* d_ws, size_t ws_size,
                              hipStream_t stream) {
  (void)in_sizes; (void)n_in; (void)out_size;
  const float* query = (const float*)d_in[0];
  const float* key = (const float*)d_in[1];
  const float* value = (const float*)d_in[2];
  const float* Wq = (const float*)d_in[4];
  const float* bq = (const float*)d_in[5];
  const float* Wk = (const float*)d_in[6];
  const float* bk = (const float*)d_in[7];
  const float* Wv = (const float*)d_in[8];
  const float* bv = (const float*)d_in[9];
  const float* Wo = (const float*)d_in[10];
  const float* bo = (const float*)d_in[11];

  char* ws = (char*)d_ws;
  const size_t SZA = (size_t)8192 * 1024 * 2;
  const size_t SZW = (size_t)1024 * 1024 * 2;
  ushort* qh = (ushort*)(ws + 0 * SZA);
  ushort* kh = (ushort*)(ws + 1 * SZA);
  ushort* vt = (ushort*)(ws + 2 * SZA);
  ushort* ao = (ushort*)(ws + 3 * SZA);
  dim3 bb(256), gg(64, 8), ga(64, 16), ba(128);
  const float QS = 0.125f * 1.44269504088896f;  // 1/sqrt(64) * log2(e)

  if (ws_size >= 4 * SZA + 4 * SZW) {
    ushort* wq = (ushort*)(ws + 4 * SZA);
    ushort* wk = (ushort*)(ws + 4 * SZA + 1 * SZW);
    ushort* wv = (ushort*)(ws + 4 * SZA + 2 * SZW);
    ushort* wo = (ushort*)(ws + 4 * SZA + 3 * SZW);
    const int n8w = 1024 * 1024 / 8;
    hipLaunchKernelGGL(cvt4_k, dim3(n8w / 256, 4), bb, 0, stream, Wq, Wk, Wv, Wo, wq, n8w);
    hipLaunchKernelGGL((gemm_k<0, 1, 0>), gg, bb, 0, stream, (const void*)query, (const void*)wq, bq, (void*)qh, QS);
    hipLaunchKernelGGL((gemm_k<0, 1, 0>), gg, bb, 0, stream, (const void*)key, (const void*)wk, bk, (void*)kh, 1.0f);
    hipLaunchKernelGGL((gemm_k<0, 1, 1>), gg, bb, 0, stream, (const void*)value, (const void*)wv, bv, (void*)vt, 1.0f);
    hipLaunchKernelGGL(attn_k, ga, ba, 0, stream, qh, kh, vt, ao);
    hipLaunchKernelGGL((gemm_k<1, 1, 2>), gg, bb, 0, stream, (const void*)ao, (const void*)wo, bo, d_out, 1.0f);
  } else {
    hipLaunchKernelGGL((gemm_k<0, 0, 0>), gg, bb, 0, stream, (const void*)query, (const void*)Wq, bq, (void*)qh, QS);
    hipLaunchKernelGGL((gemm_k<0, 0, 0>), gg, bb, 0, stream, (const void*)key, (const void*)Wk, bk, (void*)kh, 1.0f);
    hipLaunchKernelGGL((gemm_k<0, 0, 1>), gg, bb, 0, stream, (const void*)value, (const void*)Wv, bv, (void*)vt, 1.0f);
    hipLaunchKernelGGL(attn_k, ga, ba, 0, stream, qh, kh, vt, ao);
    hipLaunchKernelGGL((gemm_k<1, 0, 2>), gg, bb, 0, stream, (const void*)ao, (const void*)Wo, bo, d_out, 1.0f);
  }
}

// Round 10
// 185.991 us; speedup vs baseline: 1.1066x; 1.0869x over previous
//
#include <hip/hip_runtime.h>

typedef __bf16 bf16x8 __attribute__((ext_vector_type(8)));
typedef __bf16 bf16x2 __attribute__((ext_vector_type(2)));
typedef float f32x4 __attribute__((ext_vector_type(4)));
typedef float f32x16 __attribute__((ext_vector_type(16)));
typedef unsigned short ushort;

__device__ __forceinline__ int4 cvt8(float4 a, float4 b) {
  bf16x8 v;
  v[0] = (__bf16)a.x; v[1] = (__bf16)a.y; v[2] = (__bf16)a.z; v[3] = (__bf16)a.w;
  v[4] = (__bf16)b.x; v[5] = (__bf16)b.y; v[6] = (__bf16)b.z; v[7] = (__bf16)b.w;
  return __builtin_bit_cast(int4, v);
}

__device__ __forceinline__ void gld16(const void* g, void* l) {
  __builtin_amdgcn_global_load_lds(
      (const __attribute__((address_space(1))) void*)g,
      (__attribute__((address_space(3))) void*)l, 16, 0, 0);
}

// pack 2 f32 -> 1 dword of 2 bf16 (compiler emits v_cvt_pk_bf16_f32)
__device__ __forceinline__ unsigned pkbf(float a, float b) {
  bf16x2 v;
  v[0] = (__bf16)a;
  v[1] = (__bf16)b;
  return __builtin_bit_cast(unsigned, v);
}

// exchange: after call a = [a_lo | b_lo], b = [a_hi | b_hi] (32-lane halves)
#if __has_builtin(__builtin_amdgcn_permlane32_swap)
typedef unsigned u32x2 __attribute__((ext_vector_type(2)));
__device__ __forceinline__ void plswap(unsigned& a, unsigned& b, int hi) {
  (void)hi;
  u32x2 r = __builtin_amdgcn_permlane32_swap(a, b, false, false);
  a = r[0]; b = r[1];
}
#else
__device__ __forceinline__ void plswap(unsigned& a, unsigned& b, int hi) {
  const unsigned pa = (unsigned)__shfl_xor((int)a, 32);
  const unsigned pb = (unsigned)__shfl_xor((int)b, 32);
  const unsigned x = hi ? pb : a;
  const unsigned y = hi ? b : pa;
  a = x; b = y;
}
#endif

__device__ __forceinline__ f32x16 mfma32(bf16x8 a, bf16x8 b, f32x16 c) {
  return __builtin_amdgcn_mfma_f32_32x32x16_bf16(a, b, c, 0, 0, 0);
}

// 4 weight matrices fp32 -> bf16 in one launch (grid.y picks the matrix)
__global__ __launch_bounds__(256) void cvt4_k(const float* __restrict__ i0,
                                              const float* __restrict__ i1,
                                              const float* __restrict__ i2,
                                              const float* __restrict__ i3,
                                              ushort* __restrict__ o, int n8) {
  const int z = blockIdx.y;
  const float* in = (z == 0) ? i0 : (z == 1) ? i1 : (z == 2) ? i2 : i3;
  ushort* out = o + (size_t)z * 1024 * 1024;
  int i = blockIdx.x * 256 + threadIdx.x;
  if (i >= n8) return;
  const float4* p = (const float4*)in + (size_t)i * 2;
  *(int4*)(out + (size_t)i * 8) = cvt8(p[0], p[1]);
}

// C = (A @ W^T + bias) * oscale. M=8192, N=K=1024.
// AMODE 0: A fp32 (reg-staged+cvt); 1: A bf16 (global_load_lds).
// WMODE 0: W fp32 (reg-staged+cvt); 1: W bf16 (global_load_lds).
// OMODE 0: bf16 [B,H,S,HD]; 1: bf16 [B,H,HD,S]; 2: fp32 [M,N].
template <int AMODE, int WMODE, int OMODE>
__global__ __launch_bounds__(256) void gemm_k(const void* __restrict__ A,
                                              const void* __restrict__ W,
                                              const float* __restrict__ bias,
                                              void* __restrict__ Out,
                                              float oscale) {
  constexpr int K = 1024;
  __shared__ __align__(16) char lA[128 * 128];
  __shared__ __align__(16) char lB[128 * 128];
  const int t = threadIdx.x;
  const int l = t & 63;
  const int w = t >> 6;
  const int wr = w >> 1, wc = w & 1;
  const int m0 = blockIdx.x * 128;
  const int n0 = blockIdx.y * 128;
  const int srow = l >> 3;
  const int scol = ((l & 7) ^ srow) << 3;
  f32x4 acc[4][4];
#pragma unroll
  for (int i = 0; i < 4; ++i)
#pragma unroll
    for (int j = 0; j < 4; ++j) acc[i][j] = (f32x4){0.f, 0.f, 0.f, 0.f};

  for (int k0 = 0; k0 < K; k0 += 64) {
    if constexpr (AMODE == 1) {
#pragma unroll
      for (int i = 0; i < 4; ++i) {
        const int chunk = w * 4 + i;
        gld16((const ushort*)A + (size_t)(m0 + chunk * 8 + srow) * K + k0 + scol,
              lA + chunk * 1024);
      }
    } else {
#pragma unroll
      for (int qq = 0; qq < 4; ++qq) {
        const int L = t * 8 + qq * 2048;
        const int r = L >> 6, c = L & 63;
        const int dst = r * 128 + ((c * 2) ^ ((r & 7) << 4));
        const float* s0 = (const float*)A + (size_t)(m0 + r) * K + k0 + c;
        *(int4*)(lA + dst) = cvt8(*(const float4*)s0, *(const float4*)(s0 + 4));
      }
    }
    if constexpr (WMODE == 1) {
#pragma unroll
      for (int i = 0; i < 4; ++i) {
        const int chunk = w * 4 + i;
        gld16((const ushort*)W + (size_t)(n0 + chunk * 8 + srow) * K + k0 + scol,
              lB + chunk * 1024);
      }
    } else {
#pragma unroll
      for (int qq = 0; qq < 4; ++qq) {
        const int L = t * 8 + qq * 2048;
        const int r = L >> 6, c = L & 63;
        const int dst = r * 128 + ((c * 2) ^ ((r & 7) << 4));
        const float* s1 = (const float*)W + (size_t)(n0 + r) * K + k0 + c;
        *(int4*)(lB + dst) = cvt8(*(const float4*)s1, *(const float4*)(s1 + 4));
      }
    }
    __syncthreads();
#pragma unroll
    for (int ks = 0; ks < 2; ++ks) {
      const int kb = ks * 64 + ((l >> 4) << 4);
      bf16x8 af[4], bfv[4];
#pragma unroll
      for (int i = 0; i < 4; ++i) {
        const int row = wr * 64 + i * 16 + (l & 15);
        af[i] = *(const bf16x8*)(lA + row * 128 + (kb ^ ((row & 7) << 4)));
      }
#pragma unroll
      for (int j = 0; j < 4; ++j) {
        const int row = wc * 64 + j * 16 + (l & 15);
        bfv[j] = *(const bf16x8*)(lB + row * 128 + (kb ^ ((row & 7) << 4)));
      }
#pragma unroll
      for (int i = 0; i < 4; ++i)
#pragma unroll
        for (int j = 0; j < 4; ++j)
          acc[i][j] = __builtin_amdgcn_mfma_f32_16x16x32_bf16(af[i], bfv[j],
                                                              acc[i][j], 0, 0, 0);
    }
    __syncthreads();
  }
#pragma unroll
  for (int i = 0; i < 4; ++i)
#pragma unroll
    for (int j = 0; j < 4; ++j)
#pragma unroll
      for (int rg = 0; rg < 4; ++rg) {
        const int gm = m0 + wr * 64 + i * 16 + ((l >> 4) << 2) + rg;
        const int gn = n0 + wc * 64 + j * 16 + (l & 15);
        const float v = (acc[i][j][rg] + bias[gn]) * oscale;
        if constexpr (OMODE == 0) {
          const int b = gm >> 11, s = gm & 2047, h = gn >> 6, hd = gn & 63;
          ((ushort*)Out)[((((size_t)(b * 16 + h)) * 2048 + s) << 6) + hd] =
              __builtin_bit_cast(ushort, (__bf16)v);
        } else if constexpr (OMODE == 1) {
          const int b = gm >> 11, s = gm & 2047, h = gn >> 6, hd = gn & 63;
          ((ushort*)Out)[((((size_t)(b * 16 + h)) << 6) + hd) * 2048 + s] =
              __builtin_bit_cast(ushort, (__bf16)v);
        } else {
          ((float*)Out)[(size_t)gm * 1024 + gn] = v;
        }
      }
}

// Flash attention, causal. qh (PRE-SCALED by 0.125*log2e): [B,H,S,HD] bf16.
// kh: [B,H,S,HD] bf16. vth: [B,H,HD,S] bf16. out: [B,S,D] bf16.
// 256 thr = 4 waves x 32 q-rows (QBLK=128) -- round-5 structure (78.2us),
// + max3 tree + cvt_pk pack, VGPR pinned to the 6-waves/SIMD tier via
// __launch_bounds__(256,6). Swapped-operand MFMA 32x32x16, in-reg softmax,
// P via cvt_pk+permlane32_swap. KVBLK=64 staged (T14, named regs).
__global__ __launch_bounds__(256, 6) void attn_k(const ushort* __restrict__ qh,
                                                 const ushort* __restrict__ kh,
                                                 const ushort* __restrict__ vth,
                                                 ushort* __restrict__ out) {
  const int bh = blockIdx.x;                  // b*16 + h (fastest dim)
  const int qt = gridDim.y - 1 - blockIdx.y;  // longest tiles first
  const int q0 = qt * 128;
  const int t = threadIdx.x, l = t & 63, wv = t >> 6;
  const int lq = l & 31, hi = l >> 5;
  __shared__ __align__(16) char lk[2][64 * 128];
  __shared__ __align__(16) char lv[2][64 * 128];

  const int qrow = q0 + wv * 32 + lq;  // this lane's q (output col of S^T)
  // Q as B-operand: col = l&31 = q, k(d) = kd*16 + hi*8 + 0..7
  bf16x8 qf0, qf1, qf2, qf3;
  {
    const ushort* qp = qh + ((size_t)bh * 2048 + qrow) * 64 + hi * 8;
    qf0 = *(const bf16x8*)(qp);
    qf1 = *(const bf16x8*)(qp + 16);
    qf2 = *(const bf16x8*)(qp + 32);
    qf3 = *(const bf16x8*)(qp + 48);
  }

  const int r0 = t >> 3;
  const int c0 = (t & 7) * 8;
  const ushort* kbase = kh + (size_t)bh * 2048 * 64 + (size_t)r0 * 64 + c0;
  const ushort* vbase = vth + (size_t)bh * 64 * 2048 + (size_t)r0 * 2048 + c0;
  const int dst0 = r0 * 128 + ((c0 * 2) ^ ((r0 & 7) << 4));

  int4 ka, kb2, va, vb2;  // named -> stay in VGPRs
#define LOAD_TILE(kv0)                                            \
  do {                                                            \
    ka  = *(const int4*)(kbase + (size_t)(kv0) * 64);             \
    kb2 = *(const int4*)(kbase + (size_t)(kv0) * 64 + 32 * 64);   \
    va  = *(const int4*)(vbase + (kv0));                          \
    vb2 = *(const int4*)(vbase + (kv0) + 32 * 2048);              \
  } while (0)
#define WRITE_TILE(buf)                                           \
  do {                                                            \
    *(int4*)(lk[buf] + dst0) = ka;                                \
    *(int4*)(lk[buf] + dst0 + 32 * 128) = kb2;                    \
    *(int4*)(lv[buf] + dst0) = va;                                \
    *(int4*)(lv[buf] + dst0 + 32 * 128) = vb2;                    \
  } while (0)

  LOAD_TILE(0);
  WRITE_TILE(0);

  float m_r = -1e30f, l_r = 0.f;
  f32x16 acco[2];
#pragma unroll
  for (int dt = 0; dt < 2; ++dt)
#pragma unroll
    for (int r = 0; r < 16; ++r) acco[dt][r] = 0.f;

  const int nt = 2 * qt + 2;  // staged 64-wide KV tiles
  int cur = 0;
#pragma unroll 1
  for (int ti = 0; ti < nt; ++ti) {
    __syncthreads();
    if (ti + 1 < nt) LOAD_TILE((ti + 1) << 6);

#pragma unroll
    for (int s = 0; s < 2; ++s) {
      const int kvs = (ti << 6) + s * 32;
      if (kvs > q0 + wv * 32 + 31) continue;  // wave-uniform: above diagonal

      // S^T[kv_local][q] = K_tile . Q^T  (4 k-steps over d=64)
      f32x16 p;
#pragma unroll
      for (int r = 0; r < 16; ++r) p[r] = 0.f;
#pragma unroll
      for (int kd = 0; kd < 4; ++kd) {
        const int row = s * 32 + lq;
        const bf16x8 kf = *(const bf16x8*)(
            lk[cur] + row * 128 + ((kd * 32 + hi * 16) ^ ((row & 7) << 4)));
        const bf16x8 qf = (kd == 0) ? qf0 : (kd == 1) ? qf1 : (kd == 2) ? qf2 : qf3;
        p = mfma32(kf, qf, p);
      }
      // causal mask: kv = kvs + (r&3) + 8*(r>>2) + 4*hi ; mask if kv > qrow
      if (kvs + 31 > q0 + wv * 32) {
#pragma unroll
        for (int r = 0; r < 16; ++r) {
          const int kv = kvs + (r & 3) + 8 * (r >> 2) + 4 * hi;
          if (kv > qrow) p[r] = -1e30f;
        }
      }
      // row max: max3-fused tree (8 ops) + cross-hi
      const float a0 = fmaxf(fmaxf(p[0], p[1]), p[2]);
      const float a1 = fmaxf(fmaxf(p[3], p[4]), p[5]);
      const float a2 = fmaxf(fmaxf(p[6], p[7]), p[8]);
      const float a3 = fmaxf(fmaxf(p[9], p[10]), p[11]);
      const float a4 = fmaxf(fmaxf(p[12], p[13]), p[14]);
      const float b0 = fmaxf(fmaxf(a0, a1), a2);
      const float b1 = fmaxf(fmaxf(a3, a4), p[15]);
      float tm = fmaxf(b0, b1);
      tm = fmaxf(tm, __shfl_xor(tm, 32));
      // defer-max (T13): only rescale when max grew by > 8 (exp2 domain)
      if (!__all(tm <= m_r + 8.f)) {
        const float mn = fmaxf(m_r, tm);
        const float e = __builtin_amdgcn_exp2f(m_r - mn);
        m_r = mn;
        l_r *= e;
#pragma unroll
        for (int dt = 0; dt < 2; ++dt)
#pragma unroll
          for (int r = 0; r < 16; ++r) acco[dt][r] *= e;
      }
      // p = exp2(S - m); VALU row-sum tree
#pragma unroll
      for (int r = 0; r < 16; ++r) p[r] = __builtin_amdgcn_exp2f(p[r] - m_r);
      float sr[8];
#pragma unroll
      for (int r = 0; r < 8; ++r) sr[r] = p[r] + p[r + 8];
#pragma unroll
      for (int r = 0; r < 4; ++r) sr[r] = sr[r] + sr[r + 4];
      float rs = (sr[0] + sr[1]) + (sr[2] + sr[3]);
      rs += __shfl_xor(rs, 32);
      l_r += rs;
      // pack P pairs: W[j][i] holds kv = 8j + 4hi + 2i + {0,1}
      unsigned W0a = pkbf(p[0], p[1]),   W0b = pkbf(p[2], p[3]);
      unsigned W1a = pkbf(p[4], p[5]),   W1b = pkbf(p[6], p[7]);
      unsigned W2a = pkbf(p[8], p[9]),   W2b = pkbf(p[10], p[11]);
      unsigned W3a = pkbf(p[12], p[13]), W3b = pkbf(p[14], p[15]);
      // PV: O^T += V^T . P  (2 k-steps of 16 kv)
#pragma unroll
      for (int ks = 0; ks < 2; ++ks) {
        unsigned a0u = ks ? W2a : W0a;
        unsigned a1u = ks ? W2b : W0b;
        unsigned b0u = ks ? W3a : W1a;
        unsigned b1u = ks ? W3b : W1b;
        plswap(a0u, b0u, hi);
        plswap(a1u, b1u, hi);
        const uint4 pw = {a0u, a1u, b0u, b1u};
        const bf16x8 pf = __builtin_bit_cast(bf16x8, pw);
#pragma unroll
        for (int dt = 0; dt < 2; ++dt) {
          const int row = dt * 32 + lq;
          const bf16x8 vf = *(const bf16x8*)(
              lv[cur] + row * 128 +
              ((s * 64 + ks * 32 + hi * 16) ^ ((row & 7) << 4)));
          acco[dt] = mfma32(vf, pf, acco[dt]);
        }
      }
    }
    if (ti + 1 < nt) WRITE_TILE(cur ^ 1);
    cur ^= 1;
  }
#undef LOAD_TILE
#undef WRITE_TILE
  // epilogue: O^T lane = (q=qrow, d = (r&3)+8*(r>>2)+4*hi+32*dt)
  const int b = bh >> 4, h = bh & 15;
  const float inv = __builtin_amdgcn_rcpf(l_r);
  ushort* orow = out + ((size_t)(b * 2048 + qrow)) * 1024 + h * 64;
#pragma unroll
  for (int dt = 0; dt < 2; ++dt)
#pragma unroll
    for (int g = 0; g < 4; ++g) {
      ushort4 st;
      st.x = __builtin_bit_cast(ushort, (__bf16)(acco[dt][4 * g + 0] * inv));
      st.y = __builtin_bit_cast(ushort, (__bf16)(acco[dt][4 * g + 1] * inv));
      st.z = __builtin_bit_cast(ushort, (__bf16)(acco[dt][4 * g + 2] * inv));
      st.w = __builtin_bit_cast(ushort, (__bf16)(acco[dt][4 * g + 3] * inv));
      *(ushort4*)(orow + dt * 32 + g * 8 + hi * 4) = st;
    }
}

extern "C" void kernel_launch(void* const* d_in, const int* in_sizes, int n_in,
                              void* d_out, int out_size, void* d_ws, size_t ws_size,
                              hipStream_t stream) {
  (void)in_sizes; (void)n_in; (void)out_size;
  const float* query = (const float*)d_in[0];
  const float* key = (const float*)d_in[1];
  const float* value = (const float*)d_in[2];
  const float* Wq = (const float*)d_in[4];
  const float* bq = (const float*)d_in[5];
  const float* Wk = (const float*)d_in[6];
  const float* bk = (const float*)d_in[7];
  const float* Wv = (const float*)d_in[8];
  const float* bv = (const float*)d_in[9];
  const float* Wo = (const float*)d_in[10];
  const float* bo = (const float*)d_in[11];

  char* ws = (char*)d_ws;
  const size_t SZA = (size_t)8192 * 1024 * 2;
  const size_t SZW = (size_t)1024 * 1024 * 2;
  ushort* qh = (ushort*)(ws + 0 * SZA);
  ushort* kh = (ushort*)(ws + 1 * SZA);
  ushort* vt = (ushort*)(ws + 2 * SZA);
  ushort* ao = (ushort*)(ws + 3 * SZA);
  dim3 bb(256), gg(64, 8), ga(64, 16), ba(256);
  const float QS = 0.125f * 1.44269504088896f;  // 1/sqrt(64) * log2(e)

  if (ws_size >= 4 * SZA + 4 * SZW) {
    ushort* wq = (ushort*)(ws + 4 * SZA);
    ushort* wk = (ushort*)(ws + 4 * SZA + 1 * SZW);
    ushort* wv = (ushort*)(ws + 4 * SZA + 2 * SZW);
    ushort* wo = (ushort*)(ws + 4 * SZA + 3 * SZW);
    const int n8w = 1024 * 1024 / 8;
    hipLaunchKernelGGL(cvt4_k, dim3(n8w / 256, 4), bb, 0, stream, Wq, Wk, Wv, Wo, wq, n8w);
    hipLaunchKernelGGL((gemm_k<0, 1, 0>), gg, bb, 0, stream, (const void*)query, (const void*)wq, bq, (void*)qh, QS);
    hipLaunchKernelGGL((gemm_k<0, 1, 0>), gg, bb, 0, stream, (const void*)key, (const void*)wk, bk, (void*)kh, 1.0f);
    hipLaunchKernelGGL((gemm_k<0, 1, 1>), gg, bb, 0, stream, (const void*)value, (const void*)wv, bv, (void*)vt, 1.0f);
    hipLaunchKernelGGL(attn_k, ga, ba, 0, stream, qh, kh, vt, ao);
    hipLaunchKernelGGL((gemm_k<1, 1, 2>), gg, bb, 0, stream, (const void*)ao, (const void*)wo, bo, d_out, 1.0f);
  } else {
    hipLaunchKernelGGL((gemm_k<0, 0, 0>), gg, bb, 0, stream, (const void*)query, (const void*)Wq, bq, (void*)qh, QS);
    hipLaunchKernelGGL((gemm_k<0, 0, 0>), gg, bb, 0, stream, (const void*)key, (const void*)Wk, bk, (void*)kh, 1.0f);
    hipLaunchKernelGGL((gemm_k<0, 0, 1>), gg, bb, 0, stream, (const void*)value, (const void*)Wv, bv, (void*)vt, 1.0f);
    hipLaunchKernelGGL(attn_k, ga, ba, 0, stream, qh, kh, vt, ao);
    hipLaunchKernelGGL((gemm_k<1, 0, 2>), gg, bb, 0, stream, (const void*)ao, (const void*)Wo, bo, d_out, 1.0f);
  }
}

// Round 11
// 184.085 us; speedup vs baseline: 1.1181x; 1.0104x over previous
//
#include <hip/hip_runtime.h>

typedef __bf16 bf16x8 __attribute__((ext_vector_type(8)));
typedef __bf16 bf16x2 __attribute__((ext_vector_type(2)));
typedef float f32x4 __attribute__((ext_vector_type(4)));
typedef float f32x16 __attribute__((ext_vector_type(16)));
typedef unsigned short ushort;

__device__ __forceinline__ int4 cvt8(float4 a, float4 b) {
  bf16x8 v;
  v[0] = (__bf16)a.x; v[1] = (__bf16)a.y; v[2] = (__bf16)a.z; v[3] = (__bf16)a.w;
  v[4] = (__bf16)b.x; v[5] = (__bf16)b.y; v[6] = (__bf16)b.z; v[7] = (__bf16)b.w;
  return __builtin_bit_cast(int4, v);
}

__device__ __forceinline__ void gld16(const void* g, void* l) {
  __builtin_amdgcn_global_load_lds(
      (const __attribute__((address_space(1))) void*)g,
      (__attribute__((address_space(3))) void*)l, 16, 0, 0);
}

// pack 2 f32 -> 1 dword of 2 bf16 (compiler emits v_cvt_pk_bf16_f32)
__device__ __forceinline__ unsigned pkbf(float a, float b) {
  bf16x2 v;
  v[0] = (__bf16)a;
  v[1] = (__bf16)b;
  return __builtin_bit_cast(unsigned, v);
}

// exchange: after call a = [a_lo | b_lo], b = [a_hi | b_hi] (32-lane halves)
#if __has_builtin(__builtin_amdgcn_permlane32_swap)
typedef unsigned u32x2 __attribute__((ext_vector_type(2)));
__device__ __forceinline__ void plswap(unsigned& a, unsigned& b, int hi) {
  (void)hi;
  u32x2 r = __builtin_amdgcn_permlane32_swap(a, b, false, false);
  a = r[0]; b = r[1];
}
#else
__device__ __forceinline__ void plswap(unsigned& a, unsigned& b, int hi) {
  const unsigned pa = (unsigned)__shfl_xor((int)a, 32);
  const unsigned pb = (unsigned)__shfl_xor((int)b, 32);
  const unsigned x = hi ? pb : a;
  const unsigned y = hi ? b : pa;
  a = x; b = y;
}
#endif

__device__ __forceinline__ f32x16 mfma32(bf16x8 a, bf16x8 b, f32x16 c) {
  return __builtin_amdgcn_mfma_f32_32x32x16_bf16(a, b, c, 0, 0, 0);
}

// 4 weight matrices fp32 -> bf16 in one launch (grid.y picks the matrix)
__global__ __launch_bounds__(256) void cvt4_k(const float* __restrict__ i0,
                                              const float* __restrict__ i1,
                                              const float* __restrict__ i2,
                                              const float* __restrict__ i3,
                                              ushort* __restrict__ o, int n8) {
  const int z = blockIdx.y;
  const float* in = (z == 0) ? i0 : (z == 1) ? i1 : (z == 2) ? i2 : i3;
  ushort* out = o + (size_t)z * 1024 * 1024;
  int i = blockIdx.x * 256 + threadIdx.x;
  if (i >= n8) return;
  const float4* p = (const float4*)in + (size_t)i * 2;
  *(int4*)(out + (size_t)i * 8) = cvt8(p[0], p[1]);
}

// GEMM body as a macro so __shared__ stays kernel-scoped (AS3 preserved) and
// all modes are compile-time constants per expansion (round-8 lesson).
// C = (A @ W^T + bias) * OSCALE. M=8192, N=K=1024. BK=64, tile 128x128.
// AMODE 0: A fp32 (reg-staged+cvt); 1: A bf16 (global_load_lds).
// OMODE 0: bf16 [B,H,S,HD]; 1: bf16 [B,H,HD,S]; 2: fp32 [M,N].
#define GEMM_BODY(AMODE, OMODE, APTR, WPTR, BIASP, OUTP, OSCALE)               \
  do {                                                                         \
    constexpr int K = 1024;                                                    \
    const int t = threadIdx.x;                                                 \
    const int l = t & 63;                                                      \
    const int w = t >> 6;                                                      \
    const int wr = w >> 1, wc = w & 1;                                         \
    const int m0 = blockIdx.x * 128;                                           \
    const int n0 = blockIdx.y * 128;                                           \
    const int srow = l >> 3;                                                   \
    const int scol = ((l & 7) ^ srow) << 3;                                    \
    f32x4 acc[4][4];                                                           \
    _Pragma("unroll") for (int i = 0; i < 4; ++i)                              \
        _Pragma("unroll") for (int j = 0; j < 4; ++j)                          \
            acc[i][j] = (f32x4){0.f, 0.f, 0.f, 0.f};                           \
    for (int k0 = 0; k0 < K; k0 += 64) {                                       \
      if constexpr (AMODE == 1) {                                              \
        _Pragma("unroll") for (int i = 0; i < 4; ++i) {                        \
          const int chunk = w * 4 + i;                                         \
          gld16((const ushort*)(APTR) +                                        \
                    (size_t)(m0 + chunk * 8 + srow) * K + k0 + scol,           \
                lA + chunk * 1024);                                            \
        }                                                                      \
      } else {                                                                 \
        _Pragma("unroll") for (int qq = 0; qq < 4; ++qq) {                     \
          const int L = t * 8 + qq * 2048;                                     \
          const int r = L >> 6, c = L & 63;                                    \
          const int dst = r * 128 + ((c * 2) ^ ((r & 7) << 4));                \
          const float* s0 = (const float*)(APTR) + (size_t)(m0 + r) * K + k0 + c; \
          *(int4*)(lA + dst) = cvt8(*(const float4*)s0, *(const float4*)(s0 + 4)); \
        }                                                                      \
      }                                                                        \
      _Pragma("unroll") for (int i = 0; i < 4; ++i) {                          \
        const int chunk = w * 4 + i;                                           \
        gld16((WPTR) + (size_t)(n0 + chunk * 8 + srow) * K + k0 + scol,        \
              lB + chunk * 1024);                                              \
      }                                                                        \
      __syncthreads();                                                         \
      _Pragma("unroll") for (int ks = 0; ks < 2; ++ks) {                       \
        const int kb = ks * 64 + ((l >> 4) << 4);                              \
        bf16x8 af[4], bfv[4];                                                  \
        _Pragma("unroll") for (int i = 0; i < 4; ++i) {                        \
          const int row = wr * 64 + i * 16 + (l & 15);                         \
          af[i] = *(const bf16x8*)(lA + row * 128 + (kb ^ ((row & 7) << 4)));  \
        }                                                                      \
        _Pragma("unroll") for (int j = 0; j < 4; ++j) {                        \
          const int row = wc * 64 + j * 16 + (l & 15);                         \
          bfv[j] = *(const bf16x8*)(lB + row * 128 + (kb ^ ((row & 7) << 4))); \
        }                                                                      \
        _Pragma("unroll") for (int i = 0; i < 4; ++i)                          \
            _Pragma("unroll") for (int j = 0; j < 4; ++j)                      \
                acc[i][j] = __builtin_amdgcn_mfma_f32_16x16x32_bf16(           \
                    af[i], bfv[j], acc[i][j], 0, 0, 0);                        \
      }                                                                        \
      __syncthreads();                                                         \
    }                                                                          \
    _Pragma("unroll") for (int i = 0; i < 4; ++i)                              \
        _Pragma("unroll") for (int j = 0; j < 4; ++j)                          \
            _Pragma("unroll") for (int rg = 0; rg < 4; ++rg) {                 \
      const int gm = m0 + wr * 64 + i * 16 + ((l >> 4) << 2) + rg;             \
      const int gn = n0 + wc * 64 + j * 16 + (l & 15);                         \
      const float v = (acc[i][j][rg] + (BIASP)[gn]) * (OSCALE);                \
      if constexpr (OMODE == 0) {                                              \
        const int b = gm >> 11, s = gm & 2047, h = gn >> 6, hd = gn & 63;      \
        ((ushort*)(OUTP))[((((size_t)(b * 16 + h)) * 2048 + s) << 6) + hd] =   \
            __builtin_bit_cast(ushort, (__bf16)v);                             \
      } else if constexpr (OMODE == 1) {                                       \
        const int b = gm >> 11, s = gm & 2047, h = gn >> 6, hd = gn & 63;      \
        ((ushort*)(OUTP))[((((size_t)(b * 16 + h)) << 6) + hd) * 2048 + s] =   \
            __builtin_bit_cast(ushort, (__bf16)v);                             \
      } else {                                                                 \
        ((float*)(OUTP))[(size_t)gm * 1024 + gn] = v;                          \
      }                                                                        \
    }                                                                          \
  } while (0)

// fused QKV projections: grid.z picks {query->qh, key->kh, value->vt};
// each branch macro-expands with compile-time AMODE/OMODE.
__global__ __launch_bounds__(256) void gemmQKV_k(
    const float* __restrict__ Aq, const float* __restrict__ Ak,
    const float* __restrict__ Av, const ushort* __restrict__ Wb,
    const float* __restrict__ bq, const float* __restrict__ bk,
    const float* __restrict__ bv, ushort* __restrict__ qh,
    ushort* __restrict__ kh, ushort* __restrict__ vt, float qs) {
  __shared__ __align__(16) char lA[128 * 128];
  __shared__ __align__(16) char lB[128 * 128];
  const int z = blockIdx.z;
  if (z == 0) {
    GEMM_BODY(0, 0, Aq, Wb, bq, qh, qs);
  } else if (z == 1) {
    GEMM_BODY(0, 0, Ak, Wb + (size_t)1024 * 1024, bk, kh, 1.0f);
  } else {
    GEMM_BODY(0, 1, Av, Wb + (size_t)2 * 1024 * 1024, bv, vt, 1.0f);
  }
}

// O projection: bf16 A (gld16), fp32 out
__global__ __launch_bounds__(256) void gemmO_k(const ushort* __restrict__ A,
                                               const ushort* __restrict__ W,
                                               const float* __restrict__ bias,
                                               float* __restrict__ Out) {
  __shared__ __align__(16) char lA[128 * 128];
  __shared__ __align__(16) char lB[128 * 128];
  GEMM_BODY(1, 2, A, W, bias, Out, 1.0f);
}

// fallback GEMM (fp32 W, reg-staged) for small-ws path
template <int OMODE, int AM>
__global__ __launch_bounds__(256) void gemmF_k(const void* __restrict__ A,
                                               const float* __restrict__ Wf,
                                               const float* __restrict__ bias,
                                               void* __restrict__ Out,
                                               float oscale) {
  constexpr int K = 1024;
  __shared__ __align__(16) char lA[128 * 128];
  __shared__ __align__(16) char lB[128 * 128];
  const int t = threadIdx.x;
  const int l = t & 63;
  const int w = t >> 6;
  const int wr = w >> 1, wc = w & 1;
  const int m0 = blockIdx.x * 128;
  const int n0 = blockIdx.y * 128;
  f32x4 acc[4][4];
#pragma unroll
  for (int i = 0; i < 4; ++i)
#pragma unroll
    for (int j = 0; j < 4; ++j) acc[i][j] = (f32x4){0.f, 0.f, 0.f, 0.f};
  for (int k0 = 0; k0 < K; k0 += 64) {
#pragma unroll
    for (int qq = 0; qq < 4; ++qq) {
      const int L = t * 8 + qq * 2048;
      const int r = L >> 6, c = L & 63;
      const int dst = r * 128 + ((c * 2) ^ ((r & 7) << 4));
      if constexpr (AM == 0) {
        const float* s0 = (const float*)A + (size_t)(m0 + r) * K + k0 + c;
        *(int4*)(lA + dst) = cvt8(*(const float4*)s0, *(const float4*)(s0 + 4));
      } else {
        *(int4*)(lA + dst) =
            *(const int4*)((const ushort*)A + (size_t)(m0 + r) * K + k0 + c);
      }
      const float* s1 = Wf + (size_t)(n0 + r) * K + k0 + c;
      *(int4*)(lB + dst) = cvt8(*(const float4*)s1, *(const float4*)(s1 + 4));
    }
    __syncthreads();
#pragma unroll
    for (int ks = 0; ks < 2; ++ks) {
      const int kb = ks * 64 + ((l >> 4) << 4);
      bf16x8 af[4], bfv[4];
#pragma unroll
      for (int i = 0; i < 4; ++i) {
        const int row = wr * 64 + i * 16 + (l & 15);
        af[i] = *(const bf16x8*)(lA + row * 128 + (kb ^ ((row & 7) << 4)));
      }
#pragma unroll
      for (int j = 0; j < 4; ++j) {
        const int row = wc * 64 + j * 16 + (l & 15);
        bfv[j] = *(const bf16x8*)(lB + row * 128 + (kb ^ ((row & 7) << 4)));
      }
#pragma unroll
      for (int i = 0; i < 4; ++i)
#pragma unroll
        for (int j = 0; j < 4; ++j)
          acc[i][j] = __builtin_amdgcn_mfma_f32_16x16x32_bf16(af[i], bfv[j],
                                                              acc[i][j], 0, 0, 0);
    }
    __syncthreads();
  }
#pragma unroll
  for (int i = 0; i < 4; ++i)
#pragma unroll
    for (int j = 0; j < 4; ++j)
#pragma unroll
      for (int rg = 0; rg < 4; ++rg) {
        const int gm = m0 + wr * 64 + i * 16 + ((l >> 4) << 2) + rg;
        const int gn = n0 + wc * 64 + j * 16 + (l & 15);
        const float v = (acc[i][j][rg] + bias[gn]) * oscale;
        if constexpr (OMODE == 0) {
          const int b = gm >> 11, s = gm & 2047, h = gn >> 6, hd = gn & 63;
          ((ushort*)Out)[((((size_t)(b * 16 + h)) * 2048 + s) << 6) + hd] =
              __builtin_bit_cast(ushort, (__bf16)v);
        } else if constexpr (OMODE == 1) {
          const int b = gm >> 11, s = gm & 2047, h = gn >> 6, hd = gn & 63;
          ((ushort*)Out)[((((size_t)(b * 16 + h)) << 6) + hd) * 2048 + s] =
              __builtin_bit_cast(ushort, (__bf16)v);
        } else {
          ((float*)Out)[(size_t)gm * 1024 + gn] = v;
        }
      }
}

// Flash attention, causal. qh (PRE-SCALED by 0.125*log2e): [B,H,S,HD] bf16.
// kh: [B,H,S,HD] bf16. vth: [B,H,HD,S] bf16. out: [B,S,D] bf16.
// 256 thr = 4 waves x 32 q-rows (QBLK=128), round-10 structure (68.1us)
// + T5 setprio around MFMA clusters. VGPR pinned via __launch_bounds__(256,6).
__global__ __launch_bounds__(256, 6) void attn_k(const ushort* __restrict__ qh,
                                                 const ushort* __restrict__ kh,
                                                 const ushort* __restrict__ vth,
                                                 ushort* __restrict__ out) {
  const int bh = blockIdx.x;                  // b*16 + h (fastest dim)
  const int qt = gridDim.y - 1 - blockIdx.y;  // longest tiles first
  const int q0 = qt * 128;
  const int t = threadIdx.x, l = t & 63, wv = t >> 6;
  const int lq = l & 31, hi = l >> 5;
  __shared__ __align__(16) char lk[2][64 * 128];
  __shared__ __align__(16) char lv[2][64 * 128];

  const int qrow = q0 + wv * 32 + lq;  // this lane's q (output col of S^T)
  // Q as B-operand: col = l&31 = q, k(d) = kd*16 + hi*8 + 0..7
  bf16x8 qf0, qf1, qf2, qf3;
  {
    const ushort* qp = qh + ((size_t)bh * 2048 + qrow) * 64 + hi * 8;
    qf0 = *(const bf16x8*)(qp);
    qf1 = *(const bf16x8*)(qp + 16);
    qf2 = *(const bf16x8*)(qp + 32);
    qf3 = *(const bf16x8*)(qp + 48);
  }

  const int r0 = t >> 3;
  const int c0 = (t & 7) * 8;
  const ushort* kbase = kh + (size_t)bh * 2048 * 64 + (size_t)r0 * 64 + c0;
  const ushort* vbase = vth + (size_t)bh * 64 * 2048 + (size_t)r0 * 2048 + c0;
  const int dst0 = r0 * 128 + ((c0 * 2) ^ ((r0 & 7) << 4));

  int4 ka, kb2, va, vb2;  // named -> stay in VGPRs
#define LOAD_TILE(kv0)                                            \
  do {                                                            \
    ka  = *(const int4*)(kbase + (size_t)(kv0) * 64);             \
    kb2 = *(const int4*)(kbase + (size_t)(kv0) * 64 + 32 * 64);   \
    va  = *(const int4*)(vbase + (kv0));                          \
    vb2 = *(const int4*)(vbase + (kv0) + 32 * 2048);              \
  } while (0)
#define WRITE_TILE(buf)                                           \
  do {                                                            \
    *(int4*)(lk[buf] + dst0) = ka;                                \
    *(int4*)(lk[buf] + dst0 + 32 * 128) = kb2;                    \
    *(int4*)(lv[buf] + dst0) = va;                                \
    *(int4*)(lv[buf] + dst0 + 32 * 128) = vb2;                    \
  } while (0)

  LOAD_TILE(0);
  WRITE_TILE(0);

  float m_r = -1e30f, l_r = 0.f;
  f32x16 acco[2];
#pragma unroll
  for (int dt = 0; dt < 2; ++dt)
#pragma unroll
    for (int r = 0; r < 16; ++r) acco[dt][r] = 0.f;

  const int nt = 2 * qt + 2;  // staged 64-wide KV tiles
  int cur = 0;
#pragma unroll 1
  for (int ti = 0; ti < nt; ++ti) {
    __syncthreads();
    if (ti + 1 < nt) LOAD_TILE((ti + 1) << 6);

#pragma unroll
    for (int s = 0; s < 2; ++s) {
      const int kvs = (ti << 6) + s * 32;
      if (kvs > q0 + wv * 32 + 31) continue;  // wave-uniform: above diagonal

      // S^T[kv_local][q] = K_tile . Q^T  (4 k-steps over d=64)
      f32x16 p;
#pragma unroll
      for (int r = 0; r < 16; ++r) p[r] = 0.f;
      __builtin_amdgcn_s_setprio(1);
#pragma unroll
      for (int kd = 0; kd < 4; ++kd) {
        const int row = s * 32 + lq;
        const bf16x8 kf = *(const bf16x8*)(
            lk[cur] + row * 128 + ((kd * 32 + hi * 16) ^ ((row & 7) << 4)));
        const bf16x8 qf = (kd == 0) ? qf0 : (kd == 1) ? qf1 : (kd == 2) ? qf2 : qf3;
        p = mfma32(kf, qf, p);
      }
      __builtin_amdgcn_s_setprio(0);
      // causal mask: kv = kvs + (r&3) + 8*(r>>2) + 4*hi ; mask if kv > qrow
      if (kvs + 31 > q0 + wv * 32) {
#pragma unroll
        for (int r = 0; r < 16; ++r) {
          const int kv = kvs + (r & 3) + 8 * (r >> 2) + 4 * hi;
          if (kv > qrow) p[r] = -1e30f;
        }
      }
      // row max: max3-fused tree (8 ops) + cross-hi
      const float a0 = fmaxf(fmaxf(p[0], p[1]), p[2]);
      const float a1 = fmaxf(fmaxf(p[3], p[4]), p[5]);
      const float a2 = fmaxf(fmaxf(p[6], p[7]), p[8]);
      const float a3 = fmaxf(fmaxf(p[9], p[10]), p[11]);
      const float a4 = fmaxf(fmaxf(p[12], p[13]), p[14]);
      const float b0 = fmaxf(fmaxf(a0, a1), a2);
      const float b1 = fmaxf(fmaxf(a3, a4), p[15]);
      float tm = fmaxf(b0, b1);
      tm = fmaxf(tm, __shfl_xor(tm, 32));
      // defer-max (T13): only rescale when max grew by > 8 (exp2 domain)
      if (!__all(tm <= m_r + 8.f)) {
        const float mn = fmaxf(m_r, tm);
        const float e = __builtin_amdgcn_exp2f(m_r - mn);
        m_r = mn;
        l_r *= e;
#pragma unroll
        for (int dt = 0; dt < 2; ++dt)
#pragma unroll
          for (int r = 0; r < 16; ++r) acco[dt][r] *= e;
      }
      // p = exp2(S - m); VALU row-sum tree
#pragma unroll
      for (int r = 0; r < 16; ++r) p[r] = __builtin_amdgcn_exp2f(p[r] - m_r);
      float sr[8];
#pragma unroll
      for (int r = 0; r < 8; ++r) sr[r] = p[r] + p[r + 8];
#pragma unroll
      for (int r = 0; r < 4; ++r) sr[r] = sr[r] + sr[r + 4];
      float rs = (sr[0] + sr[1]) + (sr[2] + sr[3]);
      rs += __shfl_xor(rs, 32);
      l_r += rs;
      // pack P pairs: W[j][i] holds kv = 8j + 4hi + 2i + {0,1}
      unsigned W0a = pkbf(p[0], p[1]),   W0b = pkbf(p[2], p[3]);
      unsigned W1a = pkbf(p[4], p[5]),   W1b = pkbf(p[6], p[7]);
      unsigned W2a = pkbf(p[8], p[9]),   W2b = pkbf(p[10], p[11]);
      unsigned W3a = pkbf(p[12], p[13]), W3b = pkbf(p[14], p[15]);
      // PV: O^T += V^T . P  (2 k-steps of 16 kv)
#pragma unroll
      for (int ks = 0; ks < 2; ++ks) {
        unsigned a0u = ks ? W2a : W0a;
        unsigned a1u = ks ? W2b : W0b;
        unsigned b0u = ks ? W3a : W1a;
        unsigned b1u = ks ? W3b : W1b;
        plswap(a0u, b0u, hi);
        plswap(a1u, b1u, hi);
        const uint4 pw = {a0u, a1u, b0u, b1u};
        const bf16x8 pf = __builtin_bit_cast(bf16x8, pw);
        __builtin_amdgcn_s_setprio(1);
#pragma unroll
        for (int dt = 0; dt < 2; ++dt) {
          const int row = dt * 32 + lq;
          const bf16x8 vf = *(const bf16x8*)(
              lv[cur] + row * 128 +
              ((s * 64 + ks * 32 + hi * 16) ^ ((row & 7) << 4)));
          acco[dt] = mfma32(vf, pf, acco[dt]);
        }
        __builtin_amdgcn_s_setprio(0);
      }
    }
    if (ti + 1 < nt) WRITE_TILE(cur ^ 1);
    cur ^= 1;
  }
#undef LOAD_TILE
#undef WRITE_TILE
  // epilogue: O^T lane = (q=qrow, d = (r&3)+8*(r>>2)+4*hi+32*dt)
  const int b = bh >> 4, h = bh & 15;
  const float inv = __builtin_amdgcn_rcpf(l_r);
  ushort* orow = out + ((size_t)(b * 2048 + qrow)) * 1024 + h * 64;
#pragma unroll
  for (int dt = 0; dt < 2; ++dt)
#pragma unroll
    for (int g = 0; g < 4; ++g) {
      ushort4 st;
      st.x = __builtin_bit_cast(ushort, (__bf16)(acco[dt][4 * g + 0] * inv));
      st.y = __builtin_bit_cast(ushort, (__bf16)(acco[dt][4 * g + 1] * inv));
      st.z = __builtin_bit_cast(ushort, (__bf16)(acco[dt][4 * g + 2] * inv));
      st.w = __builtin_bit_cast(ushort, (__bf16)(acco[dt][4 * g + 3] * inv));
      *(ushort4*)(orow + dt * 32 + g * 8 + hi * 4) = st;
    }
}

extern "C" void kernel_launch(void* const* d_in, const int* in_sizes, int n_in,
                              void* d_out, int out_size, void* d_ws, size_t ws_size,
                              hipStream_t stream) {
  (void)in_sizes; (void)n_in; (void)out_size;
  const float* query = (const float*)d_in[0];
  const float* key = (const float*)d_in[1];
  const float* value = (const float*)d_in[2];
  const float* Wq = (const float*)d_in[4];
  const float* bq = (const float*)d_in[5];
  const float* Wk = (const float*)d_in[6];
  const float* bk = (const float*)d_in[7];
  const float* Wv = (const float*)d_in[8];
  const float* bv = (const float*)d_in[9];
  const float* Wo = (const float*)d_in[10];
  const float* bo = (const float*)d_in[11];

  char* ws = (char*)d_ws;
  const size_t SZA = (size_t)8192 * 1024 * 2;
  const size_t SZW = (size_t)1024 * 1024 * 2;
  ushort* qh = (ushort*)(ws + 0 * SZA);
  ushort* kh = (ushort*)(ws + 1 * SZA);
  ushort* vt = (ushort*)(ws + 2 * SZA);
  ushort* ao = (ushort*)(ws + 3 * SZA);
  dim3 bb(256), gg(64, 8), ga(64, 16), ba(256);
  const float QS = 0.125f * 1.44269504088896f;  // 1/sqrt(64) * log2(e)

  if (ws_size >= 4 * SZA + 4 * SZW) {
    ushort* wq = (ushort*)(ws + 4 * SZA);
    ushort* wo = (ushort*)(ws + 4 * SZA + 3 * SZW);
    const int n8w = 1024 * 1024 / 8;
    hipLaunchKernelGGL(cvt4_k, dim3(n8w / 256, 4), bb, 0, stream, Wq, Wk, Wv, Wo, wq, n8w);
    hipLaunchKernelGGL(gemmQKV_k, dim3(64, 8, 3), bb, 0, stream,
                       query, key, value, wq, bq, bk, bv, qh, kh, vt, QS);
    hipLaunchKernelGGL(attn_k, ga, ba, 0, stream, qh, kh, vt, ao);
    hipLaunchKernelGGL(gemmO_k, gg, bb, 0, stream, ao, wo, bo, (float*)d_out);
  } else {
    hipLaunchKernelGGL((gemmF_k<0, 0>), gg, bb, 0, stream, (const void*)query, Wq, bq, (void*)qh, QS);
    hipLaunchKernelGGL((gemmF_k<0, 0>), gg, bb, 0, stream, (const void*)key, Wk, bk, (void*)kh, 1.0f);
    hipLaunchKernelGGL((gemmF_k<1, 0>), gg, bb, 0, stream, (const void*)value, Wv, bv, (void*)vt, 1.0f);
    hipLaunchKernelGGL(attn_k, ga, ba, 0, stream, qh, kh, vt, ao);
    hipLaunchKernelGGL((gemmF_k<2, 1>), gg, bb, 0, stream, (const void*)ao, Wo, bo, d_out, 1.0f);
  }
}